// Round 1
// baseline (164.453 us; speedup 1.0000x reference)
//
#include <hip/hip_runtime.h>

// FullFixedTimeCausalConstructiveAttention — MFMA flash, split single-tile blocks.
// B=8, L=1024, H=8, E=64, HIST=512. Inputs fp32, output fp32.
// Layout: (b, l, h, e) row-major; per-(b,h) row stride = H*E = 512 floats.
//
// R1 changes vs pair-block version:
//  - 1024 blocks (one q-tile each) -> 4 blocks/CU resident (was 2): doubles the
//    number of independent serial chains per CU for latency hiding.
//  - V staging: 2-row/8-d per thread, f16x2 writes with XOR chunk swizzle
//    ((s>>3)^(d>>3)) -> 2-way banks (free); was 8-way scalar b16 scatter.
//  - softmax in base-2: scale absorbs log2(e); v_exp_f32 used directly.
#define BB   8
#define LL   1024
#define HH   8
#define EE   64
#define HIST 512
#define KSTR 72   // f16 LDS row stride: 144 B = 16B-aligned

#define SCALE2 0.18033688011112043f   // (1/sqrt(64)) * log2(e)

typedef _Float16 f16;
typedef _Float16 v8h   __attribute__((ext_vector_type(8)));
typedef _Float16 f16x2 __attribute__((ext_vector_type(2)));
typedef float    v4f   __attribute__((ext_vector_type(4)));

__device__ __forceinline__ float fexp2(float x) {
#if __has_builtin(__builtin_amdgcn_exp2f)
  return __builtin_amdgcn_exp2f(x);
#else
  return __expf(x * 0.6931471805599453f);
#endif
}

__device__ __forceinline__ void load16f(const float* __restrict__ p, float* __restrict__ f) {
  const float4* p4 = reinterpret_cast<const float4*>(p);
  float4 a = p4[0], b = p4[1], c = p4[2], d = p4[3];
  f[0]=a.x;  f[1]=a.y;  f[2]=a.z;  f[3]=a.w;
  f[4]=b.x;  f[5]=b.y;  f[6]=b.z;  f[7]=b.w;
  f[8]=c.x;  f[9]=c.y;  f[10]=c.z; f[11]=c.w;
  f[12]=d.x; f[13]=d.y; f[14]=d.z; f[15]=d.w;
}

__device__ __forceinline__ void load8f(const float* __restrict__ p, float* __restrict__ f) {
  const float4* p4 = reinterpret_cast<const float4*>(p);
  float4 a = p4[0], b = p4[1];
  f[0]=a.x; f[1]=a.y; f[2]=a.z; f[3]=a.w;
  f[4]=b.x; f[5]=b.y; f[6]=b.z; f[7]=b.w;
}

struct TileState {
  v4f   o[4];
  float m[4], l[4], pd[4];
};

// One K-tile update for one q-tile (16 rows per wave).
__device__ __forceinline__ void tile_update(
    TileState& st, const v8h* __restrict__ qf, bool dt, bool drawn,
    const f16* __restrict__ Ks, const f16* __restrict__ Vt,
    f16* __restrict__ Psw, const float* __restrict__ zd,
    int w, int ln, int lq)
{
  // ---- S = Q K^T  (C-layout: col=ln, row=lq*4+r), z in log2 units ----
  v4f S[4];
#pragma unroll
  for (int nb = 0; nb < 4; ++nb) {
    const f16* krow = &Ks[(nb * 16 + ln) * KSTR + 8 * lq];
    v8h b0 = *reinterpret_cast<const v8h*>(krow);
    v8h b1 = *reinterpret_cast<const v8h*>(krow + 32);
    v4f acc = (v4f){0.f, 0.f, 0.f, 0.f};
    acc = __builtin_amdgcn_mfma_f32_16x16x32_f16(qf[0], b0, acc, 0, 0, 0);
    acc = __builtin_amdgcn_mfma_f32_16x16x32_f16(qf[1], b1, acc, 0, 0, 0);
    S[nb] = acc;
  }

  float z[4][4];
#pragma unroll
  for (int nb = 0; nb < 4; ++nb)
#pragma unroll
    for (int r = 0; r < 4; ++r) z[nb][r] = S[nb][r] * SCALE2;

  if (dt) {
#pragma unroll
    for (int nb = 0; nb < 4; ++nb) {
      const int col = nb * 16 + ln;
#pragma unroll
      for (int r = 0; r < 4; ++r) {
        const int rowt = w * 16 + lq * 4 + r;
        if (col > rowt)                 z[nb][r] = -1e30f;     // causal mask
        else if (drawn && col == rowt)  z[nb][r] = zd[rowt];   // diag replace (log2 units)
      }
    }
  }

  // ---- online softmax (rows lq*4+r, reduce across ln lanes), base-2 ----
  float mx[4];
#pragma unroll
  for (int r = 0; r < 4; ++r)
    mx[r] = fmaxf(fmaxf(z[0][r], z[1][r]), fmaxf(z[2][r], z[3][r]));
#pragma unroll
  for (int s = 1; s < 16; s <<= 1)
#pragma unroll
    for (int r = 0; r < 4; ++r) mx[r] = fmaxf(mx[r], __shfl_xor(mx[r], s));

  float al[4];
#pragma unroll
  for (int r = 0; r < 4; ++r) {
    const float mn = fmaxf(st.m[r], mx[r]);
    al[r] = fexp2(st.m[r] - mn);
    st.m[r] = mn;
  }

  float p[4][4], rsum[4] = {0.f, 0.f, 0.f, 0.f}, pdl[4] = {0.f, 0.f, 0.f, 0.f};
#pragma unroll
  for (int nb = 0; nb < 4; ++nb) {
    const int col = nb * 16 + ln;
#pragma unroll
    for (int r = 0; r < 4; ++r) {
      const float pv = fexp2(z[nb][r] - st.m[r]);
      p[nb][r] = pv;
      rsum[r] += pv;
      if (dt && drawn && col == (w * 16 + lq * 4 + r)) pdl[r] = pv;
    }
  }
#pragma unroll
  for (int s = 1; s < 16; s <<= 1)
#pragma unroll
    for (int r = 0; r < 4; ++r) rsum[r] += __shfl_xor(rsum[r], s);
  if (dt && drawn) {
#pragma unroll
    for (int s = 1; s < 16; s <<= 1)
#pragma unroll
      for (int r = 0; r < 4; ++r) pdl[r] += __shfl_xor(pdl[r], s);
#pragma unroll
    for (int r = 0; r < 4; ++r) st.pd[r] = pdl[r];  // diag tile is last: no later rescale
  }
#pragma unroll
  for (int r = 0; r < 4; ++r) st.l[r] = st.l[r] * al[r] + rsum[r];
#pragma unroll
  for (int nb = 0; nb < 4; ++nb)
#pragma unroll
    for (int r = 0; r < 4; ++r) st.o[nb][r] *= al[r];

  // ---- P: C-layout -> A-layout via per-wave LDS (f16) ----
#pragma unroll
  for (int nb = 0; nb < 4; ++nb)
#pragma unroll
    for (int r = 0; r < 4; ++r)
      Psw[(lq * 4 + r) * KSTR + nb * 16 + ln] = (f16)p[nb][r];
  v8h pA0 = *reinterpret_cast<const v8h*>(&Psw[ln * KSTR + 8 * lq]);
  v8h pA1 = *reinterpret_cast<const v8h*>(&Psw[ln * KSTR + 32 + 8 * lq]);

  // ---- O += P V  (Vt reads use the XOR chunk swizzle) ----
#pragma unroll
  for (int nb = 0; nb < 4; ++nb) {
    const int d   = nb * 16 + ln;
    const int dsw = (d >> 3) & 7;
    const f16* vbase = &Vt[d * KSTR];
    v8h v0 = *reinterpret_cast<const v8h*>(vbase + (((lq    ) ^ dsw) & 7) * 8);
    v8h v1 = *reinterpret_cast<const v8h*>(vbase + (((lq + 4) ^ dsw) & 7) * 8);
    st.o[nb] = __builtin_amdgcn_mfma_f32_16x16x32_f16(pA0, v0, st.o[nb], 0, 0, 0);
    st.o[nb] = __builtin_amdgcn_mfma_f32_16x16x32_f16(pA1, v1, st.o[nb], 0, 0, 0);
  }
}

extern "C" __global__ __launch_bounds__(256, 4)
void ftcca_split(const float* __restrict__ Q,  const float* __restrict__ K,
                 const float* __restrict__ V,  const float* __restrict__ Qd,
                 const float* __restrict__ Kd, const float* __restrict__ Vd,
                 float* __restrict__ out)
{
  __shared__ f16   Ks[64 * KSTR];
  __shared__ f16   Vt[64 * KSTR];       // V tile transposed [d][s], s-chunks XOR-swizzled
  __shared__ f16   Ps[4][16 * KSTR];    // per-wave P round-trip buffer
  __shared__ float zdiag[64];           // diag replacement scores (log2 units)

  // bh = blockIdx & 63: all 16 q-tile blocks of one (b,h) land on one XCD -> K/V L2 reuse
  const int bh  = blockIdx.x & 63;
  const int a   = blockIdx.x >> 6;      // 0..15
  const int qt  = 15 - a;               // big K-ranges first
  const bool drawn = (qt >= 8);         // l >= 512 -> drawn rows
  const int b   = bh >> 3, h = bh & 7;
  const int t   = threadIdx.x;
  const int w    = t >> 6;
  const int lane = t & 63;
  const int ln   = lane & 15;
  const int lq   = lane >> 4;
  const int rs   = t >> 2;              // K staging row 0..63
  const int es0  = (t & 3) * 16;        // K staging dim offset
  const int vr0  = (t >> 3) * 2;        // V staging row pair 0..62
  const int vd0  = (t & 7) * 8;         // V staging dim offset

  const size_t base = ((size_t)b * LL * HH + h) * EE;
  const int ROWF = HH * EE;             // 512

  // ---- zdiag (drawn tiles only): z[l][l] = SCALE2 * (Qd[l] . Kd[l]) ----
  if (drawn) {
    const int l = qt * 64 + rs;
    const float* qrow = Qd + base + (size_t)l * ROWF + es0;
    const float* krow = Kd + base + (size_t)l * ROWF + es0;
    float par = 0.f;
#pragma unroll
    for (int i = 0; i < 16; ++i) par += qrow[i] * krow[i];
    par += __shfl_xor(par, 1);
    par += __shfl_xor(par, 2);
    if ((t & 3) == 0) zdiag[rs] = SCALE2 * par;
  }

  // ---- Q fragments (A-layout: m=ln, k=32c+8lq+j) ----
  const int rowt_q = w * 16 + ln;
  const float* qsrc = drawn ? Qd : Q;
  v8h qf[2];
  {
    const float* pq = qsrc + base + (size_t)(qt * 64 + rowt_q) * ROWF;
#pragma unroll
    for (int c = 0; c < 2; ++c) {
      const float* x = pq + 32 * c + 8 * lq;
#pragma unroll
      for (int j = 0; j < 8; ++j) qf[c][j] = (f16)x[j];
    }
  }

  TileState st;
#pragma unroll
  for (int nb = 0; nb < 4; ++nb) st.o[nb] = (v4f){0, 0, 0, 0};
#pragma unroll
  for (int r = 0; r < 4; ++r) { st.m[r] = -1e30f; st.l[r] = 0.f; st.pd[r] = 0.f; }

  // ---- prefetch K/V tile 0 into registers ----
  float tk[16], tv[16];
  load16f(K + base + (size_t)rs * ROWF + es0, tk);
  load8f(V + base + (size_t)vr0 * ROWF + vd0, tv);
  load8f(V + base + (size_t)(vr0 + 1) * ROWF + vd0, tv + 8);

  for (int i = 0; i <= qt; ++i) {
    __syncthreads();   // previous tile's LDS fully consumed
    {
      // commit register-staged tile i to LDS (f16)
      v8h k0, k1;
#pragma unroll
      for (int j = 0; j < 8; ++j) { k0[j] = (f16)tk[j]; k1[j] = (f16)tk[8 + j]; }
      v8h* kd0 = reinterpret_cast<v8h*>(&Ks[rs * KSTR + es0]);
      kd0[0] = k0;
      kd0[1] = k1;
      // V transposed: element (s=vr0+j, d) -> Vt[d*KSTR + ((s>>3)^(d>>3))*8 + (s&7)]
      const int vswz = vr0 >> 3;
#pragma unroll
      for (int dd = 0; dd < 8; ++dd) {
        const int d  = vd0 + dd;
        const int ch = (vswz ^ (d >> 3)) & 7;
        f16x2 val; val[0] = (f16)tv[dd]; val[1] = (f16)tv[8 + dd];
        *reinterpret_cast<f16x2*>(&Vt[d * KSTR + ch * 8 + (vr0 & 7)]) = val;
      }
    }
    __syncthreads();

    // issue next tile's global loads; they fly under this tile's compute
    if (i < qt) {
      const size_t r0 = (size_t)((i + 1) * 64);
      load16f(K + base + (r0 + rs) * ROWF + es0, tk);
      load8f(V + base + (r0 + vr0) * ROWF + vd0, tv);
      load8f(V + base + (r0 + vr0 + 1) * ROWF + vd0, tv + 8);
    }

    tile_update(st, qf, i == qt, drawn, Ks, Vt, Ps[w], zdiag, w, ln, lq);
  }

  // ---- epilogue ----
  float inv[4];
#pragma unroll
  for (int r = 0; r < 4; ++r) inv[r] = 1.f / st.l[r];

#pragma unroll
  for (int nb = 0; nb < 4; ++nb) {
    const int col = nb * 16 + ln;
#pragma unroll
    for (int r = 0; r < 4; ++r) {
      const int l = qt * 64 + w * 16 + lq * 4 + r;
      const size_t g = base + (size_t)l * ROWF + col;
      float val = st.o[nb][r] * inv[r];
      if (drawn) val += (st.pd[r] * inv[r]) * (Vd[g] - V[g]);  // + (pd/l)*(Vd-V)
      out[g] = val;
    }
  }
}

extern "C" void kernel_launch(void* const* d_in, const int* in_sizes, int n_in,
                              void* d_out, int out_size, void* d_ws, size_t ws_size,
                              hipStream_t stream) {
  const float* q  = (const float*)d_in[0];
  const float* k  = (const float*)d_in[1];
  const float* v  = (const float*)d_in[2];
  const float* qd = (const float*)d_in[3];
  const float* kd = (const float*)d_in[4];
  const float* vd = (const float*)d_in[5];
  // d_in[6] = attn_mask (analytic), d_in[7] = history_len (HIST)
  float* out = (float*)d_out;

  // 1024 blocks: 64 (b,h) x 16 q-tiles — 4 blocks/CU resident, big K-ranges first
  ftcca_split<<<dim3(1024), dim3(256), 0, stream>>>(q, k, v, qd, kd, vd, out);
}

// Round 2
// 156.661 us; speedup vs baseline: 1.0497x; 1.0497x over previous
//
#include <hip/hip_runtime.h>

// FullFixedTimeCausalConstructiveAttention — MFMA flash, split blocks, swapped QK^T.
// B=8, L=1024, H=8, E=64, HIST=512. Inputs fp32, output fp32.
// Layout: (b, l, h, e) row-major; per-(b,h) row stride = H*E = 512 floats.
//
// R2 change: swapped QK^T (S^T = mfma(K,Q)) so each lane owns one q-row.
//  - softmax reduce: local VALU tree + 2 ds_bpermute stages (was 4 stages x 4 rows)
//  - P write: 4x ds_write_b64 k-contiguous (was 16x b16 scatter)
//  - m/l/pd: per-lane scalars; alpha broadcast to O rows via 4 ds_bpermute
//  DS ops per tile_update per wave: 66 -> 30 (DS pipe was ~63% busy = bottleneck).
#define BB   8
#define LL   1024
#define HH   8
#define EE   64
#define HIST 512
#define KSTR 72   // f16 LDS row stride: 144 B = 16B-aligned

#define SCALE2 0.18033688011112043f   // (1/sqrt(64)) * log2(e)

typedef _Float16 f16;
typedef _Float16 v8h   __attribute__((ext_vector_type(8)));
typedef _Float16 f16x2 __attribute__((ext_vector_type(2)));
typedef _Float16 f16x4 __attribute__((ext_vector_type(4)));
typedef float    v4f   __attribute__((ext_vector_type(4)));

__device__ __forceinline__ float fexp2(float x) {
#if __has_builtin(__builtin_amdgcn_exp2f)
  return __builtin_amdgcn_exp2f(x);
#else
  return __expf(x * 0.6931471805599453f);
#endif
}

__device__ __forceinline__ void load16f(const float* __restrict__ p, float* __restrict__ f) {
  const float4* p4 = reinterpret_cast<const float4*>(p);
  float4 a = p4[0], b = p4[1], c = p4[2], d = p4[3];
  f[0]=a.x;  f[1]=a.y;  f[2]=a.z;  f[3]=a.w;
  f[4]=b.x;  f[5]=b.y;  f[6]=b.z;  f[7]=b.w;
  f[8]=c.x;  f[9]=c.y;  f[10]=c.z; f[11]=c.w;
  f[12]=d.x; f[13]=d.y; f[14]=d.z; f[15]=d.w;
}

__device__ __forceinline__ void load8f(const float* __restrict__ p, float* __restrict__ f) {
  const float4* p4 = reinterpret_cast<const float4*>(p);
  float4 a = p4[0], b = p4[1];
  f[0]=a.x; f[1]=a.y; f[2]=a.z; f[3]=a.w;
  f[4]=b.x; f[5]=b.y; f[6]=b.z; f[7]=b.w;
}

struct TileState {
  v4f   o[4];        // O accumulator, C-layout: col(d)=ln, row(q)=lq*4+r
  float m, l, pd;    // per-lane row stats for q = ln (swapped layout)
};

// One K-tile update for one q-tile. Swapped: lane (ln,lq) holds z[q=ln][k=nb*16+lq*4+r].
__device__ __forceinline__ void tile_update(
    TileState& st, const v8h* __restrict__ qf, bool dt, bool drawn,
    const f16* __restrict__ Ks, const f16* __restrict__ Vt,
    f16* __restrict__ Psw, const float* __restrict__ zd,
    int w, int ln, int lq)
{
  // ---- S^T = K Q^T  (A=K frag, B=Q frag; same registers as unswapped, roles flipped)
  v4f S[4];
#pragma unroll
  for (int nb = 0; nb < 4; ++nb) {
    const f16* krow = &Ks[(nb * 16 + ln) * KSTR + 8 * lq];
    v8h k0 = *reinterpret_cast<const v8h*>(krow);
    v8h k1 = *reinterpret_cast<const v8h*>(krow + 32);
    v4f acc = (v4f){0.f, 0.f, 0.f, 0.f};
    acc = __builtin_amdgcn_mfma_f32_16x16x32_f16(k0, qf[0], acc, 0, 0, 0);
    acc = __builtin_amdgcn_mfma_f32_16x16x32_f16(k1, qf[1], acc, 0, 0, 0);
    S[nb] = acc;
  }

  float z[4][4];
#pragma unroll
  for (int nb = 0; nb < 4; ++nb)
#pragma unroll
    for (int r = 0; r < 4; ++r) z[nb][r] = S[nb][r] * SCALE2;

  const int qlocal = w * 16 + ln;
  if (dt) {
#pragma unroll
    for (int nb = 0; nb < 4; ++nb) {
#pragma unroll
      for (int r = 0; r < 4; ++r) {
        const int klocal = nb * 16 + lq * 4 + r;
        if (klocal > qlocal)                 z[nb][r] = -1e30f;      // causal mask
        else if (drawn && klocal == qlocal)  z[nb][r] = zd[qlocal];  // diag replace
      }
    }
  }

  // ---- online softmax: local tree + 2 bpermute stages (q = ln is lane-local) ----
  float a0 = fmaxf(fmaxf(z[0][0], z[0][1]), fmaxf(z[0][2], z[0][3]));
  float a1 = fmaxf(fmaxf(z[1][0], z[1][1]), fmaxf(z[1][2], z[1][3]));
  float a2 = fmaxf(fmaxf(z[2][0], z[2][1]), fmaxf(z[2][2], z[2][3]));
  float a3 = fmaxf(fmaxf(z[3][0], z[3][1]), fmaxf(z[3][2], z[3][3]));
  float mx = fmaxf(fmaxf(a0, a1), fmaxf(a2, a3));
  mx = fmaxf(mx, __shfl_xor(mx, 16));
  mx = fmaxf(mx, __shfl_xor(mx, 32));

  const float mn = fmaxf(st.m, mx);
  const float al = fexp2(st.m - mn);
  st.m = mn;

  float p[4][4], rsum = 0.f, pdl = 0.f;
#pragma unroll
  for (int nb = 0; nb < 4; ++nb) {
#pragma unroll
    for (int r = 0; r < 4; ++r) {
      const float pv = fexp2(z[nb][r] - mn);
      p[nb][r] = pv;
      rsum += pv;
      if (dt && drawn && (nb * 16 + lq * 4 + r) == qlocal) pdl = pv;
    }
  }
  rsum += __shfl_xor(rsum, 16);
  rsum += __shfl_xor(rsum, 32);
  if (dt && drawn) {
    pdl += __shfl_xor(pdl, 16);
    pdl += __shfl_xor(pdl, 32);
    st.pd = pdl;   // diag tile is last: no later rescale
  }
  st.l = st.l * al + rsum;

  // ---- broadcast alpha into O rows (O row q = lq*4+r lives at lane ln = lq*4+r) ----
  float alO[4];
#pragma unroll
  for (int r = 0; r < 4; ++r) alO[r] = __shfl(al, lq * 4 + r);
#pragma unroll
  for (int nb = 0; nb < 4; ++nb)
#pragma unroll
    for (int r = 0; r < 4; ++r) st.o[nb][r] *= alO[r];

  // ---- P: lane owns q=ln, k = nb*16+lq*4..+3 -> k-contiguous b64 writes ----
#pragma unroll
  for (int nb = 0; nb < 4; ++nb) {
    f16x4 pk;
#pragma unroll
    for (int r = 0; r < 4; ++r) pk[r] = (f16)p[nb][r];
    *reinterpret_cast<f16x4*>(&Psw[ln * KSTR + nb * 16 + lq * 4]) = pk;
  }
  v8h pA0 = *reinterpret_cast<const v8h*>(&Psw[ln * KSTR + 8 * lq]);
  v8h pA1 = *reinterpret_cast<const v8h*>(&Psw[ln * KSTR + 32 + 8 * lq]);

  // ---- O += P V  (Vt reads use the XOR chunk swizzle) ----
#pragma unroll
  for (int nb = 0; nb < 4; ++nb) {
    const int d   = nb * 16 + ln;
    const int dsw = (d >> 3) & 7;
    const f16* vbase = &Vt[d * KSTR];
    v8h v0 = *reinterpret_cast<const v8h*>(vbase + (((lq    ) ^ dsw) & 7) * 8);
    v8h v1 = *reinterpret_cast<const v8h*>(vbase + (((lq + 4) ^ dsw) & 7) * 8);
    st.o[nb] = __builtin_amdgcn_mfma_f32_16x16x32_f16(pA0, v0, st.o[nb], 0, 0, 0);
    st.o[nb] = __builtin_amdgcn_mfma_f32_16x16x32_f16(pA1, v1, st.o[nb], 0, 0, 0);
  }
}

extern "C" __global__ __launch_bounds__(256, 4)
void ftcca_split(const float* __restrict__ Q,  const float* __restrict__ K,
                 const float* __restrict__ V,  const float* __restrict__ Qd,
                 const float* __restrict__ Kd, const float* __restrict__ Vd,
                 float* __restrict__ out)
{
  __shared__ f16   Ks[64 * KSTR];
  __shared__ f16   Vt[64 * KSTR];       // V tile transposed [d][s], s-chunks XOR-swizzled
  __shared__ f16   Ps[4][16 * KSTR];    // per-wave P round-trip buffer
  __shared__ float zdiag[64];           // diag replacement scores (log2 units)

  // bh = blockIdx & 63: all 16 q-tile blocks of one (b,h) land on one XCD -> K/V L2 reuse
  const int bh  = blockIdx.x & 63;
  const int a   = blockIdx.x >> 6;      // 0..15
  const int qt  = 15 - a;               // big K-ranges first
  const bool drawn = (qt >= 8);         // l >= 512 -> drawn rows
  const int b   = bh >> 3, h = bh & 7;
  const int t   = threadIdx.x;
  const int w    = t >> 6;
  const int lane = t & 63;
  const int ln   = lane & 15;
  const int lq   = lane >> 4;
  const int rs   = t >> 2;              // K staging row 0..63
  const int es0  = (t & 3) * 16;        // K staging dim offset
  const int vr0  = (t >> 3) * 2;        // V staging row pair 0..62
  const int vd0  = (t & 7) * 8;         // V staging dim offset

  const size_t base = ((size_t)b * LL * HH + h) * EE;
  const int ROWF = HH * EE;             // 512

  // ---- zdiag (drawn tiles only): z[l][l] = SCALE2 * (Qd[l] . Kd[l]) ----
  if (drawn) {
    const int l = qt * 64 + rs;
    const float* qrow = Qd + base + (size_t)l * ROWF + es0;
    const float* krow = Kd + base + (size_t)l * ROWF + es0;
    float par = 0.f;
#pragma unroll
    for (int i = 0; i < 16; ++i) par += qrow[i] * krow[i];
    par += __shfl_xor(par, 1);
    par += __shfl_xor(par, 2);
    if ((t & 3) == 0) zdiag[rs] = SCALE2 * par;
  }

  // ---- Q fragments (frag layout symmetric for A/B: free-dim=ln, k=32c+8lq+j) ----
  const int rowt_q = w * 16 + ln;
  const float* qsrc = drawn ? Qd : Q;
  v8h qf[2];
  {
    const float* pq = qsrc + base + (size_t)(qt * 64 + rowt_q) * ROWF;
#pragma unroll
    for (int c = 0; c < 2; ++c) {
      const float* x = pq + 32 * c + 8 * lq;
#pragma unroll
      for (int j = 0; j < 8; ++j) qf[c][j] = (f16)x[j];
    }
  }

  TileState st;
#pragma unroll
  for (int nb = 0; nb < 4; ++nb) st.o[nb] = (v4f){0, 0, 0, 0};
  st.m = -1e30f; st.l = 0.f; st.pd = 0.f;

  // ---- prefetch K/V tile 0 into registers ----
  float tk[16], tv[16];
  load16f(K + base + (size_t)rs * ROWF + es0, tk);
  load8f(V + base + (size_t)vr0 * ROWF + vd0, tv);
  load8f(V + base + (size_t)(vr0 + 1) * ROWF + vd0, tv + 8);

  for (int i = 0; i <= qt; ++i) {
    __syncthreads();   // previous tile's LDS fully consumed
    {
      // commit register-staged tile i to LDS (f16)
      v8h k0, k1;
#pragma unroll
      for (int j = 0; j < 8; ++j) { k0[j] = (f16)tk[j]; k1[j] = (f16)tk[8 + j]; }
      v8h* kd0 = reinterpret_cast<v8h*>(&Ks[rs * KSTR + es0]);
      kd0[0] = k0;
      kd0[1] = k1;
      // V transposed: element (s=vr0+j, d) -> Vt[d*KSTR + ((s>>3)^(d>>3))*8 + (s&7)]
      const int vswz = vr0 >> 3;
#pragma unroll
      for (int dd = 0; dd < 8; ++dd) {
        const int d  = vd0 + dd;
        const int ch = (vswz ^ (d >> 3)) & 7;
        f16x2 val; val[0] = (f16)tv[dd]; val[1] = (f16)tv[8 + dd];
        *reinterpret_cast<f16x2*>(&Vt[d * KSTR + ch * 8 + (vr0 & 7)]) = val;
      }
    }
    __syncthreads();

    // issue next tile's global loads; they fly under this tile's compute
    if (i < qt) {
      const size_t r0 = (size_t)((i + 1) * 64);
      load16f(K + base + (r0 + rs) * ROWF + es0, tk);
      load8f(V + base + (r0 + vr0) * ROWF + vd0, tv);
      load8f(V + base + (r0 + vr0 + 1) * ROWF + vd0, tv + 8);
    }

    tile_update(st, qf, i == qt, drawn, Ks, Vt, Ps[w], zdiag, w, ln, lq);
  }

  // ---- epilogue: broadcast l (and pd) into O rows, then store ----
  float lO[4], inv[4], pdO[4];
#pragma unroll
  for (int r = 0; r < 4; ++r) lO[r] = __shfl(st.l, lq * 4 + r);
#pragma unroll
  for (int r = 0; r < 4; ++r) inv[r] = 1.f / lO[r];
  if (drawn) {
#pragma unroll
    for (int r = 0; r < 4; ++r) pdO[r] = __shfl(st.pd, lq * 4 + r);
  }

#pragma unroll
  for (int nb = 0; nb < 4; ++nb) {
    const int col = nb * 16 + ln;
#pragma unroll
    for (int r = 0; r < 4; ++r) {
      const int l = qt * 64 + w * 16 + lq * 4 + r;
      const size_t g = base + (size_t)l * ROWF + col;
      float val = st.o[nb][r] * inv[r];
      if (drawn) val += (pdO[r] * inv[r]) * (Vd[g] - V[g]);  // + (pd/l)*(Vd-V)
      out[g] = val;
    }
  }
}

extern "C" void kernel_launch(void* const* d_in, const int* in_sizes, int n_in,
                              void* d_out, int out_size, void* d_ws, size_t ws_size,
                              hipStream_t stream) {
  const float* q  = (const float*)d_in[0];
  const float* k  = (const float*)d_in[1];
  const float* v  = (const float*)d_in[2];
  const float* qd = (const float*)d_in[3];
  const float* kd = (const float*)d_in[4];
  const float* vd = (const float*)d_in[5];
  // d_in[6] = attn_mask (analytic), d_in[7] = history_len (HIST)
  float* out = (float*)d_out;

  // 1024 blocks: 64 (b,h) x 16 q-tiles — 4 blocks/CU resident, big K-ranges first
  ftcca_split<<<dim3(1024), dim3(256), 0, stream>>>(q, k, v, qd, kd, vd, out);
}

// Round 4
// 155.460 us; speedup vs baseline: 1.0578x; 1.0077x over previous
//
#include <hip/hip_runtime.h>

// FullFixedTimeCausalConstructiveAttention — MFMA flash, split blocks, swapped QK^T,
// in-register P (K-row permutation sigma), O^T layout.
// B=8, L=1024, H=8, E=64, HIST=512. Inputs fp32, output fp32.
// Layout: (b, l, h, e) row-major; per-(b,h) row stride = H*E = 512 floats.
//
// R3 (R4 = R3 + bit_cast fix for cvt_pkrtz return type):
// the QK^T MFMAs read K-rows permuted by sigma(nb,m) = m + off[nb][m>>2],
//   off[0]={0,8,8,16} off[1]={4,4,12,12} off[2]=off[0]+32 off[3]=off[1]+32.
// => lane-quarter lq owns P[q=ln][s in {8lq..8lq+7} u {32+8lq..+7}] as f16-pairs,
//    which IS the PV B-fragment layout: P redistribution = 8 cvt_pkrtz + 8 cndmask,
//    no LDS round-trip. PV operands swapped -> O^T (col=q=ln): alpha/l/pd are
//    per-lane scalars, no broadcasts. Reduces via permlane16/32_swap (VALU,
//    variant-agnostic) instead of ds_bpermute.
#define LL   1024
#define HH   8
#define EE   64
#define KSTR 72   // f16 LDS row stride: 144 B = 16B-aligned

#define SCALE2 0.18033688011112043f   // (1/sqrt(64)) * log2(e)

typedef _Float16 f16;
typedef _Float16 v8h  __attribute__((ext_vector_type(8)));
typedef _Float16 h2   __attribute__((ext_vector_type(2)));
typedef float    v4f  __attribute__((ext_vector_type(4)));
typedef int      v2i  __attribute__((ext_vector_type(2)));

__device__ __forceinline__ float fexp2(float x) {
#if __has_builtin(__builtin_amdgcn_exp2f)
  return __builtin_amdgcn_exp2f(x);
#else
  return __expf(x * 0.6931471805599453f);
#endif
}

__device__ __forceinline__ h2 pkh2(float a, float b) {
#if __has_builtin(__builtin_amdgcn_cvt_pkrtz)
  return __builtin_bit_cast(h2, __builtin_amdgcn_cvt_pkrtz(a, b));
#else
  h2 r; r[0] = (f16)a; r[1] = (f16)b; return r;
#endif
}

// Reduce across the 4 lane-quarters (lanes ln, ln+16, ln+32, ln+48).
// permlane{16,32}_swap compositions are invariant to the odd/even-row convention.
__device__ __forceinline__ float red4max(float x) {
#if __has_builtin(__builtin_amdgcn_permlane16_swap) && __has_builtin(__builtin_amdgcn_permlane32_swap)
  int xi = __float_as_int(x);
  v2i a = __builtin_amdgcn_permlane16_swap(xi, xi, false, false);
  float m = fmaxf(__int_as_float(a.x), __int_as_float(a.y));
  int mi = __float_as_int(m);
  v2i b = __builtin_amdgcn_permlane32_swap(mi, mi, false, false);
  return fmaxf(__int_as_float(b.x), __int_as_float(b.y));
#else
  x = fmaxf(x, __shfl_xor(x, 16));
  return fmaxf(x, __shfl_xor(x, 32));
#endif
}

__device__ __forceinline__ float red4sum(float x) {
#if __has_builtin(__builtin_amdgcn_permlane16_swap) && __has_builtin(__builtin_amdgcn_permlane32_swap)
  int xi = __float_as_int(x);
  v2i a = __builtin_amdgcn_permlane16_swap(xi, xi, false, false);
  float s = __int_as_float(a.x) + __int_as_float(a.y);
  int si = __float_as_int(s);
  v2i b = __builtin_amdgcn_permlane32_swap(si, si, false, false);
  return __int_as_float(b.x) + __int_as_float(b.y);
#else
  x += __shfl_xor(x, 16);
  return x + __shfl_xor(x, 32);
#endif
}

__device__ __forceinline__ void load16f(const float* __restrict__ p, float* __restrict__ f) {
  const float4* p4 = reinterpret_cast<const float4*>(p);
  float4 a = p4[0], b = p4[1], c = p4[2], d = p4[3];
  f[0]=a.x;  f[1]=a.y;  f[2]=a.z;  f[3]=a.w;
  f[4]=b.x;  f[5]=b.y;  f[6]=b.z;  f[7]=b.w;
  f[8]=c.x;  f[9]=c.y;  f[10]=c.z; f[11]=c.w;
  f[12]=d.x; f[13]=d.y; f[14]=d.z; f[15]=d.w;
}

__device__ __forceinline__ void load8f(const float* __restrict__ p, float* __restrict__ f) {
  const float4* p4 = reinterpret_cast<const float4*>(p);
  float4 a = p4[0], b = p4[1];
  f[0]=a.x; f[1]=a.y; f[2]=a.z; f[3]=a.w;
  f[4]=b.x; f[5]=b.y; f[6]=b.z; f[7]=b.w;
}

struct TileState {
  v4f   o[4];      // O^T: lane holds O[d=16nb+4lq+r][q=w*16+ln]
  float m, l, pd;  // per-lane stats for q = ln
};

// One K-tile update. Lane (ln,lq) owns z[q=w*16+ln][s=sigma(nb,4lq+r)].
__device__ __forceinline__ void tile_update(
    TileState& st, const v8h* __restrict__ qf, bool dt, bool drawn,
    const f16* __restrict__ Ks, const f16* __restrict__ Vt,
    const float* __restrict__ zd,
    int w, int ln, int lq,
    const int* __restrict__ rk, const int* __restrict__ kb)
{
  // ---- S^T = K Q^T with permuted K rows: mfma nb, A-row m=ln <- K row rk[nb] ----
  v4f S[4];
#pragma unroll
  for (int nb = 0; nb < 4; ++nb) {
    const f16* krow = &Ks[rk[nb] * KSTR + 8 * lq];
    v8h k0 = *reinterpret_cast<const v8h*>(krow);
    v8h k1 = *reinterpret_cast<const v8h*>(krow + 32);
    v4f acc = (v4f){0.f, 0.f, 0.f, 0.f};
    acc = __builtin_amdgcn_mfma_f32_16x16x32_f16(k0, qf[0], acc, 0, 0, 0);
    acc = __builtin_amdgcn_mfma_f32_16x16x32_f16(k1, qf[1], acc, 0, 0, 0);
    S[nb] = acc;
  }

  float z[4][4];
#pragma unroll
  for (int nb = 0; nb < 4; ++nb)
#pragma unroll
    for (int r = 0; r < 4; ++r) z[nb][r] = S[nb][r] * SCALE2;

  const int qlocal = w * 16 + ln;
  if (dt) {
    const float zdq = drawn ? zd[qlocal] : 0.f;
#pragma unroll
    for (int nb = 0; nb < 4; ++nb) {
#pragma unroll
      for (int r = 0; r < 4; ++r) {
        const int kl = kb[nb] + r;             // sigma(nb, 4lq+r)
        if (kl > qlocal)                 z[nb][r] = -1e30f;  // causal mask
        else if (drawn && kl == qlocal)  z[nb][r] = zdq;     // diag replace
      }
    }
  }

  // ---- online softmax: local 16-tree + 2 permlane swaps (q=ln lane-local) ----
  float a0 = fmaxf(fmaxf(z[0][0], z[0][1]), fmaxf(z[0][2], z[0][3]));
  float a1 = fmaxf(fmaxf(z[1][0], z[1][1]), fmaxf(z[1][2], z[1][3]));
  float a2 = fmaxf(fmaxf(z[2][0], z[2][1]), fmaxf(z[2][2], z[2][3]));
  float a3 = fmaxf(fmaxf(z[3][0], z[3][1]), fmaxf(z[3][2], z[3][3]));
  const float mx = red4max(fmaxf(fmaxf(a0, a1), fmaxf(a2, a3)));

  const float mn = fmaxf(st.m, mx);
  const float al = fexp2(st.m - mn);
  st.m = mn;

  float p[4][4], rsum = 0.f, pdl = 0.f;
#pragma unroll
  for (int nb = 0; nb < 4; ++nb) {
#pragma unroll
    for (int r = 0; r < 4; ++r) {
      const float pv = fexp2(z[nb][r] - mn);
      p[nb][r] = pv;
      rsum += pv;
      if (dt && drawn && (kb[nb] + r) == qlocal) pdl = pv;
    }
  }
  rsum = red4sum(rsum);
  if (dt && drawn) st.pd = red4sum(pdl);   // diag tile is last: no later rescale
  st.l = st.l * al + rsum;
#pragma unroll
  for (int nb = 0; nb < 4; ++nb)
#pragma unroll
    for (int r = 0; r < 4; ++r) st.o[nb][r] *= al;   // per-lane scalar rescale

  // ---- P -> B-fragment in-register: owned pairs == needed k-layout by sigma ----
  h2 wq[4][2];
#pragma unroll
  for (int nb = 0; nb < 4; ++nb) {
    wq[nb][0] = pkh2(p[nb][0], p[nb][1]);
    wq[nb][1] = pkh2(p[nb][2], p[nb][3]);
  }
  const bool swp = (lq & 1);
  union U8 { v8h v; h2 h[4]; } A0, A1;
  A0.h[0] = swp ? wq[1][0] : wq[0][0];
  A0.h[1] = swp ? wq[1][1] : wq[0][1];
  A0.h[2] = swp ? wq[0][0] : wq[1][0];
  A0.h[3] = swp ? wq[0][1] : wq[1][1];
  A1.h[0] = swp ? wq[3][0] : wq[2][0];
  A1.h[1] = swp ? wq[3][1] : wq[2][1];
  A1.h[2] = swp ? wq[2][0] : wq[3][0];
  A1.h[3] = swp ? wq[2][1] : wq[3][1];

  // ---- O^T += V^T P^T: A = V-frag (d=16nb+ln), B = P-frag ----
#pragma unroll
  for (int nb = 0; nb < 4; ++nb) {
    const int d   = nb * 16 + ln;
    const int dsw = (d >> 3) & 7;
    const f16* vbase = &Vt[d * KSTR];
    v8h v0 = *reinterpret_cast<const v8h*>(vbase + (((lq    ) ^ dsw) & 7) * 8);
    v8h v1 = *reinterpret_cast<const v8h*>(vbase + (((lq + 4) ^ dsw) & 7) * 8);
    st.o[nb] = __builtin_amdgcn_mfma_f32_16x16x32_f16(v0, A0.v, st.o[nb], 0, 0, 0);
    st.o[nb] = __builtin_amdgcn_mfma_f32_16x16x32_f16(v1, A1.v, st.o[nb], 0, 0, 0);
  }
}

extern "C" __global__ __launch_bounds__(256, 4)
void ftcca_split(const float* __restrict__ Q,  const float* __restrict__ K,
                 const float* __restrict__ V,  const float* __restrict__ Qd,
                 const float* __restrict__ Kd, const float* __restrict__ Vd,
                 float* __restrict__ out)
{
  __shared__ f16   Ks[64 * KSTR];
  __shared__ f16   Vt[64 * KSTR];       // V tile transposed [d][s], s-chunks XOR-swizzled
  __shared__ float zdiag[64];           // diag replacement scores (log2 units)

  // bh = blockIdx & 63: all 16 q-tile blocks of one (b,h) land on one XCD -> K/V L2 reuse
  const int bh  = blockIdx.x & 63;
  const int a   = blockIdx.x >> 6;      // 0..15
  const int qt  = 15 - a;               // big K-ranges first
  const bool drawn = (qt >= 8);         // l >= 512 -> drawn rows
  const int b   = bh >> 3, h = bh & 7;
  const int t   = threadIdx.x;
  const int w    = t >> 6;
  const int lane = t & 63;
  const int ln   = lane & 15;
  const int lq   = lane >> 4;
  const int rs   = t >> 2;              // K staging row 0..63
  const int es0  = (t & 3) * 16;        // K staging dim offset
  const int vr0  = (t >> 3) * 2;        // V staging row pair 0..62
  const int vd0  = (t & 7) * 8;         // V staging dim offset

  const size_t base = ((size_t)b * LL * HH + h) * EE;
  const int ROWF = HH * EE;             // 512

  // sigma tables: K-frag read rows (indexed by ln) and owned-k bases (indexed by lq)
  const int q2 = ln >> 2;
  int rk[4], kb[4];
  rk[0] = ln + ((q2 + 1) >> 1) * 8;     // off[0] = {0,8,8,16}
  rk[1] = ln + 4 + (q2 >> 1) * 8;       // off[1] = {4,4,12,12}
  rk[2] = rk[0] + 32;
  rk[3] = rk[1] + 32;
  kb[0] = 4 * lq + ((lq + 1) >> 1) * 8;
  kb[1] = 4 * lq + 4 + (lq >> 1) * 8;
  kb[2] = kb[0] + 32;
  kb[3] = kb[1] + 32;

  // ---- zdiag (drawn tiles only): z[l][l] = SCALE2 * (Qd[l] . Kd[l]) ----
  if (drawn) {
    const int l = qt * 64 + rs;
    const float* qrow = Qd + base + (size_t)l * ROWF + es0;
    const float* krow = Kd + base + (size_t)l * ROWF + es0;
    float par = 0.f;
#pragma unroll
    for (int i = 0; i < 16; ++i) par += qrow[i] * krow[i];
    par += __shfl_xor(par, 1);
    par += __shfl_xor(par, 2);
    if ((t & 3) == 0) zdiag[rs] = SCALE2 * par;
  }

  // ---- Q fragments (B-operand of QK^T: free-dim=ln, k=32c+8lq+j) ----
  const int rowt_q = w * 16 + ln;
  const float* qsrc = drawn ? Qd : Q;
  v8h qf[2];
  {
    const float* pq = qsrc + base + (size_t)(qt * 64 + rowt_q) * ROWF;
#pragma unroll
    for (int c = 0; c < 2; ++c) {
      const float* x = pq + 32 * c + 8 * lq;
#pragma unroll
      for (int j = 0; j < 8; ++j) qf[c][j] = (f16)x[j];
    }
  }

  TileState st;
#pragma unroll
  for (int nb = 0; nb < 4; ++nb) st.o[nb] = (v4f){0, 0, 0, 0};
  st.m = -1e30f; st.l = 0.f; st.pd = 0.f;

  // ---- prefetch K/V tile 0 into registers ----
  float tk[16], tv[16];
  load16f(K + base + (size_t)rs * ROWF + es0, tk);
  load8f(V + base + (size_t)vr0 * ROWF + vd0, tv);
  load8f(V + base + (size_t)(vr0 + 1) * ROWF + vd0, tv + 8);

  for (int i = 0; i <= qt; ++i) {
    __syncthreads();   // previous tile's LDS fully consumed
    {
      // commit register-staged tile i to LDS (f16)
      v8h k0, k1;
#pragma unroll
      for (int j = 0; j < 8; ++j) { k0[j] = (f16)tk[j]; k1[j] = (f16)tk[8 + j]; }
      v8h* kd0 = reinterpret_cast<v8h*>(&Ks[rs * KSTR + es0]);
      kd0[0] = k0;
      kd0[1] = k1;
      // V transposed: element (s=vr0+j, d) -> Vt[d*KSTR + ((s>>3)^(d>>3))*8 + (s&7)]
      const int vswz = vr0 >> 3;
#pragma unroll
      for (int dd = 0; dd < 8; ++dd) {
        const int d  = vd0 + dd;
        const int ch = (vswz ^ (d >> 3)) & 7;
        h2 val; val[0] = (f16)tv[dd]; val[1] = (f16)tv[8 + dd];
        *reinterpret_cast<h2*>(&Vt[d * KSTR + ch * 8 + (vr0 & 7)]) = val;
      }
    }
    __syncthreads();

    // issue next tile's global loads; they fly under this tile's compute
    if (i < qt) {
      const size_t r0 = (size_t)((i + 1) * 64);
      load16f(K + base + (r0 + rs) * ROWF + es0, tk);
      load8f(V + base + (r0 + vr0) * ROWF + vd0, tv);
      load8f(V + base + (r0 + vr0 + 1) * ROWF + vd0, tv + 8);
    }

    tile_update(st, qf, i == qt, drawn, Ks, Vt, zdiag, w, ln, lq, rk, kb);
  }

  // ---- epilogue: O^T store — per-lane scalars, float4 per nb ----
  const float inv = 1.f / st.l;
  const float pdinv = st.pd * inv;
  const int lrow = qt * 64 + w * 16 + ln;

#pragma unroll
  for (int nb = 0; nb < 4; ++nb) {
    const int d0 = nb * 16 + lq * 4;
    const size_t g = base + (size_t)lrow * ROWF + d0;
    float4 o4;
    o4.x = st.o[nb][0] * inv;
    o4.y = st.o[nb][1] * inv;
    o4.z = st.o[nb][2] * inv;
    o4.w = st.o[nb][3] * inv;
    if (drawn) {
      float4 vd4 = *reinterpret_cast<const float4*>(Vd + g);
      float4 v4  = *reinterpret_cast<const float4*>(V + g);
      o4.x += pdinv * (vd4.x - v4.x);
      o4.y += pdinv * (vd4.y - v4.y);
      o4.z += pdinv * (vd4.z - v4.z);
      o4.w += pdinv * (vd4.w - v4.w);
    }
    *reinterpret_cast<float4*>(out + g) = o4;
  }
}

extern "C" void kernel_launch(void* const* d_in, const int* in_sizes, int n_in,
                              void* d_out, int out_size, void* d_ws, size_t ws_size,
                              hipStream_t stream) {
  const float* q  = (const float*)d_in[0];
  const float* k  = (const float*)d_in[1];
  const float* v  = (const float*)d_in[2];
  const float* qd = (const float*)d_in[3];
  const float* kd = (const float*)d_in[4];
  const float* vd = (const float*)d_in[5];
  // d_in[6] = attn_mask (analytic), d_in[7] = history_len (HIST)
  float* out = (float*)d_out;

  // 1024 blocks: 64 (b,h) x 16 q-tiles — big K-ranges first
  ftcca_split<<<dim3(1024), dim3(256), 0, stream>>>(q, k, v, qd, kd, vd, out);
}

// Round 5
// 151.023 us; speedup vs baseline: 1.0889x; 1.0294x over previous
//
#include <hip/hip_runtime.h>

// FullFixedTimeCausalConstructiveAttention — MFMA flash, paired q-tiles, swapped QK^T,
// in-register P (sigma permutation), O^T layout, shared K/V fragment reads.
// B=8, L=1024, H=8, E=64, HIST=512. Inputs fp32, output fp32.
// Layout: (b, l, h, e) row-major; per-(b,h) row stride = H*E = 512 floats.
//
// R5 = R4's cheap tile update + R0's pair balance:
//  - 512 blocks: pair (qtA=15-a, qtB=a): uniform 17 tile-units/block, no drain tail.
//  - each wave owns subtile w of BOTH tiles: K/V fragments read ONCE per iter and
//    feed both chains (halves dominant DS-read traffic on shared iters), and the
//    two independent softmax chains give per-wave ILP.
//  - launch_bounds(256,2): grid is 2 blocks/CU; VGPR cap 256 (no occupancy cost).
#define LL   1024
#define HH   8
#define EE   64
#define KSTR 72   // f16 LDS row stride: 144 B = 16B-aligned

#define SCALE2 0.18033688011112043f   // (1/sqrt(64)) * log2(e)

typedef _Float16 f16;
typedef _Float16 v8h  __attribute__((ext_vector_type(8)));
typedef _Float16 h2   __attribute__((ext_vector_type(2)));
typedef float    v4f  __attribute__((ext_vector_type(4)));
typedef int      v2i  __attribute__((ext_vector_type(2)));

union U8 { v8h v; h2 h[4]; };

__device__ __forceinline__ float fexp2(float x) {
#if __has_builtin(__builtin_amdgcn_exp2f)
  return __builtin_amdgcn_exp2f(x);
#else
  return __expf(x * 0.6931471805599453f);
#endif
}

__device__ __forceinline__ h2 pkh2(float a, float b) {
#if __has_builtin(__builtin_amdgcn_cvt_pkrtz)
  return __builtin_bit_cast(h2, __builtin_amdgcn_cvt_pkrtz(a, b));
#else
  h2 r; r[0] = (f16)a; r[1] = (f16)b; return r;
#endif
}

// Reduce across the 4 lane-quarters (lanes ln, ln+16, ln+32, ln+48).
__device__ __forceinline__ float red4max(float x) {
#if __has_builtin(__builtin_amdgcn_permlane16_swap) && __has_builtin(__builtin_amdgcn_permlane32_swap)
  int xi = __float_as_int(x);
  v2i a = __builtin_amdgcn_permlane16_swap(xi, xi, false, false);
  float m = fmaxf(__int_as_float(a.x), __int_as_float(a.y));
  int mi = __float_as_int(m);
  v2i b = __builtin_amdgcn_permlane32_swap(mi, mi, false, false);
  return fmaxf(__int_as_float(b.x), __int_as_float(b.y));
#else
  x = fmaxf(x, __shfl_xor(x, 16));
  return fmaxf(x, __shfl_xor(x, 32));
#endif
}

__device__ __forceinline__ float red4sum(float x) {
#if __has_builtin(__builtin_amdgcn_permlane16_swap) && __has_builtin(__builtin_amdgcn_permlane32_swap)
  int xi = __float_as_int(x);
  v2i a = __builtin_amdgcn_permlane16_swap(xi, xi, false, false);
  float s = __int_as_float(a.x) + __int_as_float(a.y);
  int si = __float_as_int(s);
  v2i b = __builtin_amdgcn_permlane32_swap(si, si, false, false);
  return __int_as_float(b.x) + __int_as_float(b.y);
#else
  x += __shfl_xor(x, 16);
  return x + __shfl_xor(x, 32);
#endif
}

__device__ __forceinline__ void load16f(const float* __restrict__ p, float* __restrict__ f) {
  const float4* p4 = reinterpret_cast<const float4*>(p);
  float4 a = p4[0], b = p4[1], c = p4[2], d = p4[3];
  f[0]=a.x;  f[1]=a.y;  f[2]=a.z;  f[3]=a.w;
  f[4]=b.x;  f[5]=b.y;  f[6]=b.z;  f[7]=b.w;
  f[8]=c.x;  f[9]=c.y;  f[10]=c.z; f[11]=c.w;
  f[12]=d.x; f[13]=d.y; f[14]=d.z; f[15]=d.w;
}

__device__ __forceinline__ void load8f(const float* __restrict__ p, float* __restrict__ f) {
  const float4* p4 = reinterpret_cast<const float4*>(p);
  float4 a = p4[0], b = p4[1];
  f[0]=a.x; f[1]=a.y; f[2]=a.z; f[3]=a.w;
  f[4]=b.x; f[5]=b.y; f[6]=b.z; f[7]=b.w;
}

struct TileState {
  v4f   o[4];      // O^T: lane holds O[d=16nb+4lq+r][q = tile_base + w*16 + ln]
  float m, l, pd;  // per-lane stats for this tile's q-row
};

// Softmax + P-fragment pack for one chain. S in C-layout of the swapped QK^T:
// lane (ln,lq) holds z[q=w*16+ln][s = sigma(nb,4lq+r)] (kb = owned-k bases).
__device__ __forceinline__ void softmax_pack(
    TileState& st, const v4f* __restrict__ S, bool dt, bool drawn, float zdq,
    int qlocal, const int* __restrict__ kb, int lq, U8& A0, U8& A1)
{
  float z[4][4];
#pragma unroll
  for (int nb = 0; nb < 4; ++nb)
#pragma unroll
    for (int r = 0; r < 4; ++r) z[nb][r] = S[nb][r] * SCALE2;

  if (dt) {
#pragma unroll
    for (int nb = 0; nb < 4; ++nb) {
#pragma unroll
      for (int r = 0; r < 4; ++r) {
        const int kl = kb[nb] + r;             // sigma(nb, 4lq+r)
        if (kl > qlocal)                 z[nb][r] = -1e30f;  // causal mask
        else if (drawn && kl == qlocal)  z[nb][r] = zdq;     // diag replace
      }
    }
  }

  float a0 = fmaxf(fmaxf(z[0][0], z[0][1]), fmaxf(z[0][2], z[0][3]));
  float a1 = fmaxf(fmaxf(z[1][0], z[1][1]), fmaxf(z[1][2], z[1][3]));
  float a2 = fmaxf(fmaxf(z[2][0], z[2][1]), fmaxf(z[2][2], z[2][3]));
  float a3 = fmaxf(fmaxf(z[3][0], z[3][1]), fmaxf(z[3][2], z[3][3]));
  const float mx = red4max(fmaxf(fmaxf(a0, a1), fmaxf(a2, a3)));

  const float mn = fmaxf(st.m, mx);
  const float al = fexp2(st.m - mn);
  st.m = mn;

  float p[4][4], rsum = 0.f, pdl = 0.f;
#pragma unroll
  for (int nb = 0; nb < 4; ++nb) {
#pragma unroll
    for (int r = 0; r < 4; ++r) {
      const float pv = fexp2(z[nb][r] - mn);
      p[nb][r] = pv;
      rsum += pv;
      if (dt && drawn && (kb[nb] + r) == qlocal) pdl = pv;
    }
  }
  rsum = red4sum(rsum);
  if (dt && drawn) st.pd = red4sum(pdl);   // diag tile is last: no later rescale
  st.l = st.l * al + rsum;
#pragma unroll
  for (int nb = 0; nb < 4; ++nb)
#pragma unroll
    for (int r = 0; r < 4; ++r) st.o[nb][r] *= al;   // per-lane scalar rescale

  // P -> PV B-fragment in-register (sigma makes owned pairs == needed k-layout)
  h2 wq[4][2];
#pragma unroll
  for (int nb = 0; nb < 4; ++nb) {
    wq[nb][0] = pkh2(p[nb][0], p[nb][1]);
    wq[nb][1] = pkh2(p[nb][2], p[nb][3]);
  }
  const bool swp = (lq & 1);
  A0.h[0] = swp ? wq[1][0] : wq[0][0];
  A0.h[1] = swp ? wq[1][1] : wq[0][1];
  A0.h[2] = swp ? wq[0][0] : wq[1][0];
  A0.h[3] = swp ? wq[0][1] : wq[1][1];
  A1.h[0] = swp ? wq[3][0] : wq[2][0];
  A1.h[1] = swp ? wq[3][1] : wq[2][1];
  A1.h[2] = swp ? wq[2][0] : wq[3][0];
  A1.h[3] = swp ? wq[2][1] : wq[3][1];
}

extern "C" __global__ __launch_bounds__(256, 2)
void ftcca_pair2(const float* __restrict__ Q,  const float* __restrict__ K,
                 const float* __restrict__ V,  const float* __restrict__ Qd,
                 const float* __restrict__ Kd, const float* __restrict__ Vd,
                 float* __restrict__ out)
{
  __shared__ f16   Ks[64 * KSTR];
  __shared__ f16   Vt[64 * KSTR];       // V tile transposed [d][s], s-chunks XOR-swizzled
  __shared__ float zdiag[64];           // diag replacement scores for tile A (log2 units)

  // bh = blockIdx & 63: the 8 pair-blocks of one (b,h) land on one XCD (L2 share)
  const int bh  = blockIdx.x & 63;
  const int a   = blockIdx.x >> 6;      // 0..7
  const int qtA = 15 - a;               // >= 8 -> all rows drawn
  const int qtB = a;                    // <= 7 -> no rows drawn
  const int b   = bh >> 3, h = bh & 7;
  const int t   = threadIdx.x;
  const int w    = t >> 6;
  const int lane = t & 63;
  const int ln   = lane & 15;
  const int lq   = lane >> 4;
  const int rs   = t >> 2;              // K staging row 0..63
  const int es0  = (t & 3) * 16;        // K staging dim offset
  const int vr0  = (t >> 3) * 2;        // V staging row pair 0..62
  const int vd0  = (t & 7) * 8;         // V staging dim offset

  const size_t base = ((size_t)b * LL * HH + h) * EE;
  const int ROWF = HH * EE;             // 512

  // sigma tables: K-frag read rows (indexed by ln) and owned-k bases (indexed by lq)
  const int q2 = ln >> 2;
  int rk[4], kb[4];
  rk[0] = ln + ((q2 + 1) >> 1) * 8;     // off[0] = {0,8,8,16}
  rk[1] = ln + 4 + (q2 >> 1) * 8;       // off[1] = {4,4,12,12}
  rk[2] = rk[0] + 32;
  rk[3] = rk[1] + 32;
  kb[0] = 4 * lq + ((lq + 1) >> 1) * 8;
  kb[1] = 4 * lq + 4 + (lq >> 1) * 8;
  kb[2] = kb[0] + 32;
  kb[3] = kb[1] + 32;

  // ---- zdiag for tile A: z[l][l] = SCALE2 * (Qd[l] . Kd[l]) ----
  {
    const int l = qtA * 64 + rs;
    const float* qrow = Qd + base + (size_t)l * ROWF + es0;
    const float* krow = Kd + base + (size_t)l * ROWF + es0;
    float par = 0.f;
#pragma unroll
    for (int i = 0; i < 16; ++i) par += qrow[i] * krow[i];
    par += __shfl_xor(par, 1);
    par += __shfl_xor(par, 2);
    if ((t & 3) == 0) zdiag[rs] = SCALE2 * par;
  }

  // ---- Q fragments for both tiles (B-operand of QK^T: free-dim=ln, k=32c+8lq+j) ----
  const int rowt_q = w * 16 + ln;
  v8h qfA[2], qfB[2];
  {
    const float* pa = Qd + base + (size_t)(qtA * 64 + rowt_q) * ROWF;
    const float* pb = Q  + base + (size_t)(qtB * 64 + rowt_q) * ROWF;
#pragma unroll
    for (int c = 0; c < 2; ++c) {
      const float* xa = pa + 32 * c + 8 * lq;
      const float* xb = pb + 32 * c + 8 * lq;
#pragma unroll
      for (int j = 0; j < 8; ++j) { qfA[c][j] = (f16)xa[j]; qfB[c][j] = (f16)xb[j]; }
    }
  }

  TileState stA, stB;
#pragma unroll
  for (int nb = 0; nb < 4; ++nb) { stA.o[nb] = (v4f){0,0,0,0}; stB.o[nb] = (v4f){0,0,0,0}; }
  stA.m = -1e30f; stA.l = 0.f; stA.pd = 0.f;
  stB.m = -1e30f; stB.l = 0.f; stB.pd = 0.f;

  const int qlocal = w * 16 + ln;       // within-tile q row (same for A and B)

  // ---- prefetch K/V tile 0 into registers ----
  float tk[16], tv[16];
  load16f(K + base + (size_t)rs * ROWF + es0, tk);
  load8f(V + base + (size_t)vr0 * ROWF + vd0, tv);
  load8f(V + base + (size_t)(vr0 + 1) * ROWF + vd0, tv + 8);

  for (int i = 0; i <= qtA; ++i) {
    __syncthreads();   // previous tile's LDS fully consumed
    {
      // commit register-staged tile i to LDS (f16)
      v8h k0, k1;
#pragma unroll
      for (int j = 0; j < 8; ++j) { k0[j] = (f16)tk[j]; k1[j] = (f16)tk[8 + j]; }
      v8h* kd0 = reinterpret_cast<v8h*>(&Ks[rs * KSTR + es0]);
      kd0[0] = k0;
      kd0[1] = k1;
      // V transposed: element (s=vr0+j, d) -> Vt[d*KSTR + ((s>>3)^(d>>3))*8 + (s&7)]
      const int vswz = vr0 >> 3;
#pragma unroll
      for (int dd = 0; dd < 8; ++dd) {
        const int d  = vd0 + dd;
        const int ch = (vswz ^ (d >> 3)) & 7;
        h2 val; val[0] = (f16)tv[dd]; val[1] = (f16)tv[8 + dd];
        *reinterpret_cast<h2*>(&Vt[d * KSTR + ch * 8 + (vr0 & 7)]) = val;
      }
    }
    __syncthreads();

    // issue next tile's global loads; they fly under this tile's compute
    if (i < qtA) {
      const size_t r0 = (size_t)((i + 1) * 64);
      load16f(K + base + (r0 + rs) * ROWF + es0, tk);
      load8f(V + base + (r0 + vr0) * ROWF + vd0, tv);
      load8f(V + base + (r0 + vr0 + 1) * ROWF + vd0, tv + 8);
    }

    const bool doB = (i <= qtB);
    const bool dtA = (i == qtA);
    const bool dtB = (i == qtB);

    // ---- K fragments read ONCE, feed both chains ----
    v8h k0f[4], k1f[4];
#pragma unroll
    for (int nb = 0; nb < 4; ++nb) {
      const f16* krow = &Ks[rk[nb] * KSTR + 8 * lq];
      k0f[nb] = *reinterpret_cast<const v8h*>(krow);
      k1f[nb] = *reinterpret_cast<const v8h*>(krow + 32);
    }

    v4f SA[4], SB[4];
#pragma unroll
    for (int nb = 0; nb < 4; ++nb) {
      v4f acc = (v4f){0.f, 0.f, 0.f, 0.f};
      acc = __builtin_amdgcn_mfma_f32_16x16x32_f16(k0f[nb], qfA[0], acc, 0, 0, 0);
      acc = __builtin_amdgcn_mfma_f32_16x16x32_f16(k1f[nb], qfA[1], acc, 0, 0, 0);
      SA[nb] = acc;
    }
    if (doB) {
#pragma unroll
      for (int nb = 0; nb < 4; ++nb) {
        v4f acc = (v4f){0.f, 0.f, 0.f, 0.f};
        acc = __builtin_amdgcn_mfma_f32_16x16x32_f16(k0f[nb], qfB[0], acc, 0, 0, 0);
        acc = __builtin_amdgcn_mfma_f32_16x16x32_f16(k1f[nb], qfB[1], acc, 0, 0, 0);
        SB[nb] = acc;
      }
    }

    // ---- two independent softmax chains (ILP) ----
    U8 pA0, pA1, pB0, pB1;
    const float zdq = dtA ? zdiag[qlocal] : 0.f;
    softmax_pack(stA, SA, dtA, true,  zdq, qlocal, kb, lq, pA0, pA1);
    if (doB)
      softmax_pack(stB, SB, dtB, false, 0.f, qlocal, kb, lq, pB0, pB1);

    // ---- V fragments read ONCE, feed both PV chains ----
#pragma unroll
    for (int nb = 0; nb < 4; ++nb) {
      const int d   = nb * 16 + ln;
      const int dsw = (d >> 3) & 7;
      const f16* vbase = &Vt[d * KSTR];
      v8h v0 = *reinterpret_cast<const v8h*>(vbase + (((lq    ) ^ dsw) & 7) * 8);
      v8h v1 = *reinterpret_cast<const v8h*>(vbase + (((lq + 4) ^ dsw) & 7) * 8);
      stA.o[nb] = __builtin_amdgcn_mfma_f32_16x16x32_f16(v0, pA0.v, stA.o[nb], 0, 0, 0);
      stA.o[nb] = __builtin_amdgcn_mfma_f32_16x16x32_f16(v1, pA1.v, stA.o[nb], 0, 0, 0);
      if (doB) {
        stB.o[nb] = __builtin_amdgcn_mfma_f32_16x16x32_f16(v0, pB0.v, stB.o[nb], 0, 0, 0);
        stB.o[nb] = __builtin_amdgcn_mfma_f32_16x16x32_f16(v1, pB1.v, stB.o[nb], 0, 0, 0);
      }
    }
  }

  // ---- epilogue: O^T stores — per-lane scalars, float4 per nb ----
  {
    const float inv = 1.f / stA.l;
    const float pdinv = stA.pd * inv;
    const int lrow = qtA * 64 + w * 16 + ln;
#pragma unroll
    for (int nb = 0; nb < 4; ++nb) {
      const int d0 = nb * 16 + lq * 4;
      const size_t g = base + (size_t)lrow * ROWF + d0;
      float4 vd4 = *reinterpret_cast<const float4*>(Vd + g);
      float4 v4  = *reinterpret_cast<const float4*>(V + g);
      float4 o4;
      o4.x = stA.o[nb][0] * inv + pdinv * (vd4.x - v4.x);
      o4.y = stA.o[nb][1] * inv + pdinv * (vd4.y - v4.y);
      o4.z = stA.o[nb][2] * inv + pdinv * (vd4.z - v4.z);
      o4.w = stA.o[nb][3] * inv + pdinv * (vd4.w - v4.w);
      *reinterpret_cast<float4*>(out + g) = o4;
    }
  }
  {
    const float inv = 1.f / stB.l;
    const int lrow = qtB * 64 + w * 16 + ln;
#pragma unroll
    for (int nb = 0; nb < 4; ++nb) {
      const int d0 = nb * 16 + lq * 4;
      const size_t g = base + (size_t)lrow * ROWF + d0;
      float4 o4;
      o4.x = stB.o[nb][0] * inv;
      o4.y = stB.o[nb][1] * inv;
      o4.z = stB.o[nb][2] * inv;
      o4.w = stB.o[nb][3] * inv;
      *reinterpret_cast<float4*>(out + g) = o4;
    }
  }
}

extern "C" void kernel_launch(void* const* d_in, const int* in_sizes, int n_in,
                              void* d_out, int out_size, void* d_ws, size_t ws_size,
                              hipStream_t stream) {
  const float* q  = (const float*)d_in[0];
  const float* k  = (const float*)d_in[1];
  const float* v  = (const float*)d_in[2];
  const float* qd = (const float*)d_in[3];
  const float* kd = (const float*)d_in[4];
  const float* vd = (const float*)d_in[5];
  // d_in[6] = attn_mask (analytic), d_in[7] = history_len (HIST)
  float* out = (float*)d_out;

  // 512 blocks: 64 (b,h) x 8 pairs — uniform 17 tile-units per block, no drain
  ftcca_pair2<<<dim3(512), dim3(256), 0, stream>>>(q, k, v, qd, kd, vd, out);
}